// Round 1
// baseline (196.292 us; speedup 1.0000x reference)
//
#include <hip/hip_runtime.h>
#include <math.h>

#define NATOMS 50000
#define NNEIGH 48
#define ZMAXV 87
#define NREFV 7
#define NFREQV 23
#define KCNV 7
#define XPAD 24
#define ATOMS_PER_BLOCK 4
#define PAIR_BLOCK (ATOMS_PER_BLOCK * NNEIGH) /* 192 */

#define C2BOHR 1.8897261258369282f
#define C2EV 13.605693012183622f
#define K2C 1.33333333333333333f
#define K4C 4.10451f
#define K5C 19.08857f
#define K6INV (1.0f / 254.5553148552f)
#define KNC 7.5f
#define EXP_GA 20.085536923187668f /* e^3 */
#define SQRT3 1.7320508075688772f

__device__ __forceinline__ float sp(float x) { return log1pf(expf(x)); }

// ---------------------------------------------------------------------------
// k_setup: softplus scalars, reference alpha table [87][7][24], zero outputs 1,2
// ---------------------------------------------------------------------------
__global__ __launch_bounds__(256) void k_setup(
    const int* __restrict__ refsys, const float* __restrict__ zeff,
    const float* __restrict__ refh, const float* __restrict__ sscale,
    const float* __restrict__ secaiw, const float* __restrict__ gam,
    const float* __restrict__ ascale, const float* __restrict__ alphaiw,
    const float* __restrict__ hcount,
    const float* __restrict__ s6r, const float* __restrict__ s8r,
    const float* __restrict__ a1r, const float* __restrict__ a2r,
    const float* __restrict__ sqr,
    float* __restrict__ scal_out, float* __restrict__ alpha_out,
    float* __restrict__ zero_out)
{
    int e = blockIdx.x * 256 + threadIdx.x;
    if (e == 0) {
        scal_out[0] = sp(s6r[0]);
        scal_out[1] = sp(s8r[0]);
        scal_out[2] = sp(a1r[0]);
        scal_out[3] = sp(a2r[0]);
    }
    if (e < 2 * NATOMS) zero_out[e] = 0.0f; // outputs 1 and 2 (zeros)
    if (e < ZMAXV * NREFV * XPAD) {
        int x = e % XPAD;
        int za = e / XPAD; // z*NREF + a
        float v = 0.0f;
        if (x < NFREQV) {
            float scaleq = sp(sqr[0]);
            int rs = refsys[za];
            float iz = zeff[rs];
            float qmod = iz + refh[za] * scaleq;
            float zeta = (qmod > 1e-8f)
                ? __expf(3.0f * (1.0f - __expf(gam[rs] * 2.0f * (1.0f - iz / qmod))))
                : EXP_GA;
            float asec = sscale[rs] * secaiw[rs * NFREQV + x] * zeta;
            v = fmaxf(ascale[za] * (alphaiw[za * NFREQV + x] - hcount[za] * asec), 0.0f);
        }
        alpha_out[e] = v;
    }
}

// ---------------------------------------------------------------------------
// k_atoms: 4 atoms/block. covcn (segmented sum over 48 contiguous pairs) ->
// gweights -> zeta -> A[atom][24] with sqrt(cpw*3/pi) folded in.
// ---------------------------------------------------------------------------
__global__ __launch_bounds__(PAIR_BLOCK) void k_atoms(
    const int* __restrict__ Z, const int* __restrict__ idx_j,
    const float* __restrict__ r_ij, const float* __restrict__ qa,
    const float* __restrict__ sqr, const float* __restrict__ zeff,
    const float* __restrict__ gam, const float* __restrict__ rcov,
    const float* __restrict__ en, const float* __restrict__ nmask,
    const float* __restrict__ nweight, const float* __restrict__ cn,
    const float* __restrict__ fixg, const float* __restrict__ refq,
    const float* __restrict__ cpw, const float* __restrict__ alpha_tab,
    float* __restrict__ A_out)
{
    __shared__ float sh[PAIR_BLOCK];
    __shared__ float covcn[ATOMS_PER_BLOCK];
    __shared__ float gwl[ATOMS_PER_BLOCK][NREFV];
    __shared__ float ztl[ATOMS_PER_BLOCK][NREFV];
    const int t = threadIdx.x;
    const int a0 = blockIdx.x * ATOMS_PER_BLOCK;

    // Phase A: per-pair CN contribution
    {
        int p = blockIdx.x * PAIR_BLOCK + t;
        int atom = a0 + (t / NNEIGH);
        int zi = Z[atom];
        int j = idx_j[p];
        int zj = Z[j];
        float r = r_ij[p] * C2BOHR;
        float rco = K2C * (rcov[zi] + rcov[zj]);
        float d = fabsf(en[zi] - en[zj]) + K5C;
        float den = K4C * __expf(-d * d * K6INV);
        float tmp = den * 0.5f * (1.0f + erff(-KNC * (r - rco) / rco));
        sh[t] = tmp;
    }
    __syncthreads();
    if (t < ATOMS_PER_BLOCK) {
        float s = 0.0f;
        for (int k = 0; k < NNEIGH; k++) s += sh[t * NNEIGH + k];
        covcn[t] = s;
    }
    __syncthreads();

    // Phase B: raw gaussian weights per (atom, ref)
    if (t < ATOMS_PER_BLOCK * NREFV) {
        int al = t / NREFV, a = t % NREFV;
        int zl = Z[a0 + al];
        float cc = covcn[al];
        const float* mB = nmask + (zl * NREFV + a) * KCNV;
        const float* wB = nweight + (zl * NREFV + a) * KCNV;
        const float* cB = cn + (zl * NREFV + a) * KCNV;
        float g = 0.0f;
        for (int k = 0; k < KCNV; k++) {
            float dc = cc - cB[k];
            g += mB[k] * __expf(-6.0f * wB[k] * dc * dc);
        }
        gwl[al][a] = g;
    }
    __syncthreads();

    // Phase C: normalize, charge-scaling zeta, zt = zeta * gweight
    if (t < ATOMS_PER_BLOCK * NREFV) {
        int al = t / NREFV, a = t % NREFV;
        int zl = Z[a0 + al];
        float norm = 0.0f;
        for (int b = 0; b < NREFV; b++) norm += gwl[al][b];
        float w = (norm > 1e-8f) ? (gwl[al][a] / norm) : fixg[zl * NREFV + a];
        float scaleq = sp(sqr[0]);
        float iz = zeff[zl];
        float qref = iz + refq[zl * NREFV + a] * scaleq;
        float qmod = iz + qa[a0 + al];
        float zeta = (qmod > 1e-8f)
            ? __expf(3.0f * (1.0f - __expf(gam[zl] * 2.0f * (1.0f - qref / qmod))))
            : EXP_GA;
        ztl[al][a] = zeta * w;
    }
    __syncthreads();

    // Phase D: A[atom][x] = sqrt(cpw[x]*3/pi) * sum_a zt[a]*alpha[Z,a,x]
    if (t < ATOMS_PER_BLOCK * XPAD) {
        int al = t / XPAD, x = t % XPAD;
        float v = 0.0f;
        if (x < NFREQV) {
            int zl = Z[a0 + al];
            float s = 0.0f;
            #pragma unroll
            for (int a = 0; a < NREFV; a++)
                s += ztl[al][a] * alpha_tab[(zl * NREFV + a) * XPAD + x];
            v = s * sqrtf(cpw[x] * 0.9549296585513721f);
        }
        A_out[a0 * XPAD + t] = v; // coalesced: 96 consecutive floats
    }
}

// ---------------------------------------------------------------------------
// k_pairs: c6ij = dot24(A_i, A_j); rational damping; segmented sum -> eatom
// ---------------------------------------------------------------------------
__global__ __launch_bounds__(PAIR_BLOCK) void k_pairs(
    const int* __restrict__ Z, const int* __restrict__ idx_j,
    const float* __restrict__ r_ij, const float* __restrict__ scal,
    const float* __restrict__ sr4r2, const float* __restrict__ A,
    float* __restrict__ eatom)
{
    __shared__ float sh[PAIR_BLOCK];
    __shared__ float Ai[ATOMS_PER_BLOCK * XPAD];
    const int t = threadIdx.x;
    const int a0 = blockIdx.x * ATOMS_PER_BLOCK;

    if (t < ATOMS_PER_BLOCK * XPAD) Ai[t] = A[a0 * XPAD + t];
    __syncthreads();

    const float s6 = scal[0], s8 = scal[1], a1 = scal[2], a2 = scal[3];

    int p = blockIdx.x * PAIR_BLOCK + t;
    int al = t / NNEIGH;
    int atom = a0 + al;
    int j = idx_j[p];
    int zi = Z[atom], zj = Z[j];
    float r = r_ij[p] * C2BOHR;

    const float4* Aj4 = (const float4*)(A + (size_t)j * XPAD);
    const float* Aib = Ai + al * XPAD;
    float c6 = 0.0f;
    #pragma unroll
    for (int q = 0; q < XPAD / 4; q++) {
        float4 v = Aj4[q];
        c6 += v.x * Aib[4 * q + 0] + v.y * Aib[4 * q + 1] +
              v.z * Aib[4 * q + 2] + v.w * Aib[4 * q + 3];
    }

    float r4r2 = SQRT3 * sr4r2[zi] * sr4r2[zj];
    float r0 = a1 * r4r2 + a2;
    float r2 = r * r, r4 = r2 * r2, r6 = r4 * r2, r8 = r4 * r4;
    float p2 = r0 * r0, p4 = p2 * p2, p6 = p4 * p2, p8 = p4 * p4;
    float oor6 = 1.0f / (r6 + p6);
    float oor8 = 1.0f / (r8 + p8);
    float e = -c6 * (s6 * oor6 + s8 * r4r2 * r4r2 * oor8) * C2EV;

    sh[t] = e;
    __syncthreads();
    if (t < ATOMS_PER_BLOCK) {
        float s = 0.0f;
        for (int k = 0; k < NNEIGH; k++) s += sh[t * NNEIGH + k];
        eatom[a0 + t] = s;
    }
}

// ---------------------------------------------------------------------------
extern "C" void kernel_launch(void* const* d_in, const int* in_sizes, int n_in,
                              void* d_out, int out_size, void* d_ws, size_t ws_size,
                              hipStream_t stream)
{
    const int*   Z       = (const int*)  d_in[0];
    /* d_in[1] = idx_i: known structure repeat(arange(N),48), unused */
    const int*   idx_j   = (const int*)  d_in[2];
    const float* r_ij    = (const float*)d_in[3];
    const float* qa      = (const float*)d_in[4];
    const float* s6r     = (const float*)d_in[5];
    const float* s8r     = (const float*)d_in[6];
    const float* a1r     = (const float*)d_in[7];
    const float* a2r     = (const float*)d_in[8];
    const float* sqraw   = (const float*)d_in[9];
    const int*   refsys  = (const int*)  d_in[10];
    const float* zeff    = (const float*)d_in[11];
    const float* refh    = (const float*)d_in[12];
    const float* sscale  = (const float*)d_in[13];
    const float* secaiw  = (const float*)d_in[14];
    const float* gam     = (const float*)d_in[15];
    const float* ascale  = (const float*)d_in[16];
    const float* alphaiw = (const float*)d_in[17];
    const float* hcount  = (const float*)d_in[18];
    const float* cpw     = (const float*)d_in[19];
    const float* rcov    = (const float*)d_in[20];
    const float* en      = (const float*)d_in[21];
    const float* nmask   = (const float*)d_in[22];
    const float* nweight = (const float*)d_in[23];
    const float* cn      = (const float*)d_in[24];
    const float* fixg    = (const float*)d_in[25];
    const float* refq    = (const float*)d_in[26];
    const float* sr4r2   = (const float*)d_in[27];

    float* ws    = (float*)d_ws;
    float* scal  = ws;                               // 16 floats (4 used)
    float* alpha = ws + 16;                          // 87*7*24 = 14616 floats
    float* Avec  = ws + 16 + ZMAXV * NREFV * XPAD;   // 50000*24 floats (16B aligned)

    float* eatom = (float*)d_out;
    float* zeros = eatom + NATOMS;

    k_setup<<<391, 256, 0, stream>>>(refsys, zeff, refh, sscale, secaiw, gam,
                                     ascale, alphaiw, hcount, s6r, s8r, a1r, a2r,
                                     sqraw, scal, alpha, zeros);
    k_atoms<<<NATOMS / ATOMS_PER_BLOCK, PAIR_BLOCK, 0, stream>>>(
        Z, idx_j, r_ij, qa, sqraw, zeff, gam, rcov, en,
        nmask, nweight, cn, fixg, refq, cpw, alpha, Avec);
    k_pairs<<<NATOMS / ATOMS_PER_BLOCK, PAIR_BLOCK, 0, stream>>>(
        Z, idx_j, r_ij, scal, sr4r2, Avec, eatom);
}

// Round 3
// 177.704 us; speedup vs baseline: 1.1046x; 1.1046x over previous
//
#include <hip/hip_runtime.h>
#include <hip/hip_fp16.h>
#include <math.h>

#define NATOMS 50000
#define NNEIGH 48
#define ZMAXV 87
#define NREFV 7
#define NFREQV 23
#define KCNV 7
#define XPAD 24          /* fp32 alpha table row pad */
#define XPADH 32         /* fp16 A-row pad: 32 halfs = 64 B */
#define ATOMS_PER_BLOCK 4
#define PAIR_BLOCK (ATOMS_PER_BLOCK * NNEIGH) /* 192 */

#define C2BOHR 1.8897261258369282f
#define C2EV 13.605693012183622f
#define K2C 1.33333333333333333f
#define K4C 4.10451f
#define K5C 19.08857f
#define K6INV (1.0f / 254.5553148552f)
#define KNC 7.5f
#define EXP_GA 20.085536923187668f /* e^3 */
#define QRT3 1.3160740129524924f   /* 3^(1/4); folded so r4r2 = s'_i * s'_j */

__device__ __forceinline__ float sp(float x) { return log1pf(expf(x)); }

// ---------------------------------------------------------------------------
// k_setup: softplus scalars, reference alpha table [87][7][24], per-atom
// {rcov,en} float2, zero outputs 1,2
// ---------------------------------------------------------------------------
__global__ __launch_bounds__(256) void k_setup(
    const int* __restrict__ Z, const int* __restrict__ refsys,
    const float* __restrict__ zeff, const float* __restrict__ refh,
    const float* __restrict__ sscale, const float* __restrict__ secaiw,
    const float* __restrict__ gam, const float* __restrict__ ascale,
    const float* __restrict__ alphaiw, const float* __restrict__ hcount,
    const float* __restrict__ rcov, const float* __restrict__ en,
    const float* __restrict__ s6r, const float* __restrict__ s8r,
    const float* __restrict__ a1r, const float* __restrict__ a2r,
    const float* __restrict__ sqr,
    float* __restrict__ scal_out, float* __restrict__ alpha_out,
    float2* __restrict__ re2_out, float* __restrict__ zero_out)
{
    int e = blockIdx.x * 256 + threadIdx.x;
    if (e == 0) {
        scal_out[0] = sp(s6r[0]);
        scal_out[1] = sp(s8r[0]);
        scal_out[2] = sp(a1r[0]);
        scal_out[3] = sp(a2r[0]);
    }
    if (e < 2 * NATOMS) zero_out[e] = 0.0f; // outputs 1 and 2 (zeros)
    if (e < NATOMS) {
        int z = Z[e];
        re2_out[e] = make_float2(rcov[z], en[z]);
    }
    if (e < ZMAXV * NREFV * XPAD) {
        int x = e % XPAD;
        int za = e / XPAD; // z*NREF + a
        float v = 0.0f;
        if (x < NFREQV) {
            float scaleq = sp(sqr[0]);
            int rs = refsys[za];
            float iz = zeff[rs];
            float qmod = iz + refh[za] * scaleq;
            float zeta = (qmod > 1e-8f)
                ? __expf(3.0f * (1.0f - __expf(gam[rs] * 2.0f * (1.0f - iz / qmod))))
                : EXP_GA;
            float asec = sscale[rs] * secaiw[rs * NFREQV + x] * zeta;
            v = fmaxf(ascale[za] * (alphaiw[za * NFREQV + x] - hcount[za] * asec), 0.0f);
        }
        alpha_out[e] = v;
    }
}

// ---------------------------------------------------------------------------
// k_atoms: 4 atoms/block. covcn (segmented sum over 48 contiguous pairs) ->
// gweights -> zeta -> fp16 A-row [32 halfs]: x<23 = sqrt(cpw*3/pi)*sum_a
// zt*alpha ; x==23 = 3^(1/4)*sqrt_r4r2[Z] ; rest 0.
// ---------------------------------------------------------------------------
__global__ __launch_bounds__(PAIR_BLOCK) void k_atoms(
    const int* __restrict__ Z, const int* __restrict__ idx_j,
    const float* __restrict__ r_ij, const float* __restrict__ qa,
    const float* __restrict__ sqr, const float* __restrict__ zeff,
    const float* __restrict__ gam, const float2* __restrict__ re2,
    const float* __restrict__ nmask, const float* __restrict__ nweight,
    const float* __restrict__ cn, const float* __restrict__ fixg,
    const float* __restrict__ refq, const float* __restrict__ cpw,
    const float* __restrict__ alpha_tab, const float* __restrict__ sr4r2,
    __half* __restrict__ A_out)
{
    __shared__ float sh[PAIR_BLOCK];
    __shared__ float covcn[ATOMS_PER_BLOCK];
    __shared__ float gwl[ATOMS_PER_BLOCK][NREFV];
    __shared__ float ztl[ATOMS_PER_BLOCK][NREFV];
    const int t = threadIdx.x;
    const int a0 = blockIdx.x * ATOMS_PER_BLOCK;

    // Phase A: per-pair CN contribution
    {
        int p = blockIdx.x * PAIR_BLOCK + t;
        int atom = a0 + (t / NNEIGH);
        float2 rei = re2[atom];
        float2 rej = re2[idx_j[p]];
        float r = r_ij[p] * C2BOHR;
        float rco = K2C * (rei.x + rej.x);
        float d = fabsf(rei.y - rej.y) + K5C;
        float den = K4C * __expf(-d * d * K6INV);
        sh[t] = den * 0.5f * (1.0f + erff(-KNC * (r - rco) / rco));
    }
    __syncthreads();
    if (t < ATOMS_PER_BLOCK) {
        float s = 0.0f;
        for (int k = 0; k < NNEIGH; k++) s += sh[t * NNEIGH + k];
        covcn[t] = s;
    }
    __syncthreads();

    // Phase B: raw gaussian weights per (atom, ref)
    if (t < ATOMS_PER_BLOCK * NREFV) {
        int al = t / NREFV, a = t % NREFV;
        int zl = Z[a0 + al];
        float cc = covcn[al];
        const float* mB = nmask + (zl * NREFV + a) * KCNV;
        const float* wB = nweight + (zl * NREFV + a) * KCNV;
        const float* cB = cn + (zl * NREFV + a) * KCNV;
        float g = 0.0f;
        for (int k = 0; k < KCNV; k++) {
            float dc = cc - cB[k];
            g += mB[k] * __expf(-6.0f * wB[k] * dc * dc);
        }
        gwl[al][a] = g;
    }
    __syncthreads();

    // Phase C: normalize, charge-scaling zeta, zt = zeta * gweight
    if (t < ATOMS_PER_BLOCK * NREFV) {
        int al = t / NREFV, a = t % NREFV;
        int zl = Z[a0 + al];
        float norm = 0.0f;
        for (int b = 0; b < NREFV; b++) norm += gwl[al][b];
        float w = (norm > 1e-8f) ? (gwl[al][a] / norm) : fixg[zl * NREFV + a];
        float scaleq = sp(sqr[0]);
        float iz = zeff[zl];
        float qref = iz + refq[zl * NREFV + a] * scaleq;
        float qmod = iz + qa[a0 + al];
        float zeta = (qmod > 1e-8f)
            ? __expf(3.0f * (1.0f - __expf(gam[zl] * 2.0f * (1.0f - qref / qmod))))
            : EXP_GA;
        ztl[al][a] = zeta * w;
    }
    __syncthreads();

    // Phase D: fp16 A-row write, coalesced (t -> a0*32 + t)
    if (t < ATOMS_PER_BLOCK * XPADH) {
        int al = t / XPADH, x = t % XPADH;
        int zl = Z[a0 + al];
        float v = 0.0f;
        if (x < NFREQV) {
            float s = 0.0f;
            #pragma unroll
            for (int a = 0; a < NREFV; a++)
                s += ztl[al][a] * alpha_tab[(zl * NREFV + a) * XPAD + x];
            v = s * sqrtf(cpw[x] * 0.9549296585513721f);
        } else if (x == NFREQV) {
            v = QRT3 * sr4r2[zl];
        }
        A_out[(size_t)a0 * XPADH + t] = __float2half(v);
    }
}

// ---------------------------------------------------------------------------
// k_pairs: c6ij = dot23(A_i, A_j) (fp16 rows, fp32 accumulate); rational
// damping; segmented sum -> eatom. No Z / sr4r2 gathers (slot 23 carries s').
// ---------------------------------------------------------------------------
__global__ __launch_bounds__(PAIR_BLOCK) void k_pairs(
    const int* __restrict__ idx_j, const float* __restrict__ r_ij,
    const float* __restrict__ scal, const __half* __restrict__ Ah,
    float* __restrict__ eatom)
{
    __shared__ float sh[PAIR_BLOCK];
    __shared__ float Ai[ATOMS_PER_BLOCK][NFREQV];
    __shared__ float Asi[ATOMS_PER_BLOCK];
    const int t = threadIdx.x;
    const int a0 = blockIdx.x * ATOMS_PER_BLOCK;

    if (t < ATOMS_PER_BLOCK * XPADH) {
        int al = t >> 5, x = t & 31;
        float v = __half2float(Ah[(size_t)a0 * XPADH + t]);
        if (x < NFREQV) Ai[al][x] = v;
        else if (x == NFREQV) Asi[al] = v;
    }
    __syncthreads();

    const float s6 = scal[0], s8 = scal[1], a1 = scal[2], a2 = scal[3];

    int p = blockIdx.x * PAIR_BLOCK + t;
    int al = t / NNEIGH;
    int j = idx_j[p];
    float r = r_ij[p] * C2BOHR;

    const float4* Aj4 = (const float4*)(Ah + (size_t)j * XPADH);
    float4 w0 = Aj4[0], w1 = Aj4[1], w2 = Aj4[2];
    float a[24];
    {
        const __half2* h0 = (const __half2*)&w0;
        const __half2* h1 = (const __half2*)&w1;
        const __half2* h2 = (const __half2*)&w2;
        #pragma unroll
        for (int k = 0; k < 4; k++) {
            float2 f0 = __half22float2(h0[k]);
            float2 f1 = __half22float2(h1[k]);
            float2 f2 = __half22float2(h2[k]);
            a[2 * k]      = f0.x; a[2 * k + 1]      = f0.y;
            a[8 + 2 * k]  = f1.x; a[8 + 2 * k + 1]  = f1.y;
            a[16 + 2 * k] = f2.x; a[16 + 2 * k + 1] = f2.y;
        }
    }
    float c6 = 0.0f;
    #pragma unroll
    for (int x = 0; x < NFREQV; x++) c6 += a[x] * Ai[al][x];
    float sj = a[NFREQV];

    float r4r2 = Asi[al] * sj;          // 3^(1/4) folded into both factors
    float r0 = a1 * r4r2 + a2;
    float r2 = r * r, r4 = r2 * r2, r6 = r4 * r2, r8 = r4 * r4;
    float p2 = r0 * r0, p4 = p2 * p2, p6 = p4 * p2, p8 = p4 * p4;
    float oor6 = 1.0f / (r6 + p6);
    float oor8 = 1.0f / (r8 + p8);
    float e = -c6 * (s6 * oor6 + s8 * r4r2 * r4r2 * oor8) * C2EV;

    sh[t] = e;
    __syncthreads();
    if (t < ATOMS_PER_BLOCK) {
        float s = 0.0f;
        for (int k = 0; k < NNEIGH; k++) s += sh[t * NNEIGH + k];
        eatom[a0 + t] = s;
    }
}

// ---------------------------------------------------------------------------
extern "C" void kernel_launch(void* const* d_in, const int* in_sizes, int n_in,
                              void* d_out, int out_size, void* d_ws, size_t ws_size,
                              hipStream_t stream)
{
    const int*   Z       = (const int*)  d_in[0];
    /* d_in[1] = idx_i: known structure repeat(arange(N),48), unused */
    const int*   idx_j   = (const int*)  d_in[2];
    const float* r_ij    = (const float*)d_in[3];
    const float* qa      = (const float*)d_in[4];
    const float* s6r     = (const float*)d_in[5];
    const float* s8r     = (const float*)d_in[6];
    const float* a1r     = (const float*)d_in[7];
    const float* a2r     = (const float*)d_in[8];
    const float* sqraw   = (const float*)d_in[9];
    const int*   refsys  = (const int*)  d_in[10];
    const float* zeff    = (const float*)d_in[11];
    const float* refh    = (const float*)d_in[12];
    const float* sscale  = (const float*)d_in[13];
    const float* secaiw  = (const float*)d_in[14];
    const float* gam     = (const float*)d_in[15];
    const float* ascale  = (const float*)d_in[16];
    const float* alphaiw = (const float*)d_in[17];
    const float* hcount  = (const float*)d_in[18];
    const float* cpw     = (const float*)d_in[19];
    const float* rcov    = (const float*)d_in[20];
    const float* en      = (const float*)d_in[21];
    const float* nmask   = (const float*)d_in[22];
    const float* nweight = (const float*)d_in[23];
    const float* cn      = (const float*)d_in[24];
    const float* fixg    = (const float*)d_in[25];
    const float* refq    = (const float*)d_in[26];
    const float* sr4r2   = (const float*)d_in[27];

    float* ws    = (float*)d_ws;
    float* scal  = ws;                                    // floats [0,16)
    float* alpha = ws + 16;                               // 87*7*24 = 14616 floats
    float2* re2  = (float2*)(ws + 16 + ZMAXV * NREFV * XPAD);   // 50000 float2 (8B aligned)
    __half* Ah   = (__half*)(ws + 16 + ZMAXV * NREFV * XPAD + 2 * NATOMS); // 16B aligned
    // offsets: 16+14616 = 14632 floats (58528 B, /8 ok); +100000 -> 114632 floats
    // = 458528 B, /16 ok. Ah = 50000*32 halfs = 3.2 MB.

    float* eatom = (float*)d_out;
    float* zeros = eatom + NATOMS;

    k_setup<<<391, 256, 0, stream>>>(Z, refsys, zeff, refh, sscale, secaiw, gam,
                                     ascale, alphaiw, hcount, rcov, en,
                                     s6r, s8r, a1r, a2r, sqraw,
                                     scal, alpha, re2, zeros);
    k_atoms<<<NATOMS / ATOMS_PER_BLOCK, PAIR_BLOCK, 0, stream>>>(
        Z, idx_j, r_ij, qa, sqraw, zeff, gam, re2,
        nmask, nweight, cn, fixg, refq, cpw, alpha, sr4r2, Ah);
    k_pairs<<<NATOMS / ATOMS_PER_BLOCK, PAIR_BLOCK, 0, stream>>>(
        idx_j, r_ij, scal, Ah, eatom);
}